// Round 1
// baseline (112.747 us; speedup 1.0000x reference)
//
#include <hip/hip_runtime.h>

#define N 8192
#define D 128

using short8  = __attribute__((ext_vector_type(8))) short;
using float4v = __attribute__((ext_vector_type(4))) float;

// float -> bf16 (RNE) as raw ushort
static __device__ inline unsigned int f2bf(float f) {
    union { float f; unsigned int u; } x;
    x.f = f;
    unsigned int u = x.u;
    return (u + 0x7FFFu + ((u >> 16) & 1u)) >> 16;
}

// Main kernel: each block owns 128 rows x 1024 columns of the 8192x8192
// similarity matrix. Grid = (64 row-blocks, 8 column-splits) = 512 blocks.
// Per-row partial sums (total / positive) accumulated via atomicAdd.
__global__ __launch_bounds__(256, 2) void cl_main(
    const float* __restrict__ emb, const int* __restrict__ labels,
    float* __restrict__ tot, float* __restrict__ pos)
{
    __shared__ uint4 ldsB[128 * 16];  // 128 rows x 128 bf16, as 16B chunks, XOR-swizzled (32 KB)

    const int tid  = threadIdx.x;
    const int lane = tid & 63;
    const int wave = tid >> 6;
    const int q    = lane >> 4;   // quad id 0..3
    const int c    = lane & 15;   // low-4 lane id
    const int rb   = blockIdx.x * 128;
    const int rw   = rb + wave * 32;          // this wave's 32-row base

    // ---- A fragments: load this wave's 32 rows once, fp32->bf16 in regs ----
    // A-operand layout (16x16x32): m = lane&15, k = q*8 + j  (j=0..7)
    short8 afrag[2][4];
    int rowlab[2][4];
    #pragma unroll
    for (int tr = 0; tr < 2; ++tr) {
        const int arow = rw + tr * 16 + c;
        #pragma unroll
        for (int ks = 0; ks < 4; ++ks) {
            const float* p = emb + arow * D + ks * 32 + q * 8;
            float4v f0 = *(const float4v*)p;
            float4v f1 = *(const float4v*)(p + 4);
            short8 a;
            a[0] = (short)f2bf(f0[0]); a[1] = (short)f2bf(f0[1]);
            a[2] = (short)f2bf(f0[2]); a[3] = (short)f2bf(f0[3]);
            a[4] = (short)f2bf(f1[0]); a[5] = (short)f2bf(f1[1]);
            a[6] = (short)f2bf(f1[2]); a[7] = (short)f2bf(f1[3]);
            afrag[tr][ks] = a;
        }
        // C/D layout rows this lane owns: rw + tr*16 + q*4 + reg
        #pragma unroll
        for (int reg = 0; reg < 4; ++reg)
            rowlab[tr][reg] = labels[rw + tr * 16 + q * 4 + reg];
    }

    float tot_a[2][4] = {{0.f,0.f,0.f,0.f},{0.f,0.f,0.f,0.f}};
    float pos_a[2][4] = {{0.f,0.f,0.f,0.f},{0.f,0.f,0.f,0.f}};
    const float invT = 1.0f / 0.07f;

    for (int it = 0; it < 8; ++it) {
        const int cbase = blockIdx.y * 1024 + it * 128;

        // ---- stage 128x128 column tile: global fp32 -> bf16 LDS (swizzled) ----
        // chunk = 8 bf16 = 16 B; 16 chunks/row; chunk slot ^= (row & 15)
        #pragma unroll
        for (int i = 0; i < 8; ++i) {
            const int g     = tid + i * 256;
            const int brow  = g >> 4;
            const int chunk = g & 15;
            const float* p = emb + (cbase + brow) * D + chunk * 8;
            float4v f0 = *(const float4v*)p;
            float4v f1 = *(const float4v*)(p + 4);
            uint4 u;
            u.x = f2bf(f0[0]) | (f2bf(f0[1]) << 16);
            u.y = f2bf(f0[2]) | (f2bf(f0[3]) << 16);
            u.z = f2bf(f1[0]) | (f2bf(f1[1]) << 16);
            u.w = f2bf(f1[2]) | (f2bf(f1[3]) << 16);
            ldsB[brow * 16 + (chunk ^ (brow & 15))] = u;
        }
        // column labels for this tile (L1/L2-hot 32 KB array)
        int collab[8];
        #pragma unroll
        for (int tc = 0; tc < 8; ++tc) collab[tc] = labels[cbase + tc * 16 + c];
        __syncthreads();

        // ---- MFMA: 2 tile-rows x 8 tile-cols, K=128 in 4 steps ----
        float4v acc[2][8];
        #pragma unroll
        for (int tr = 0; tr < 2; ++tr)
            #pragma unroll
            for (int tc = 0; tc < 8; ++tc) {
                float4v z = {0.f, 0.f, 0.f, 0.f};
                acc[tr][tc] = z;
            }

        const short8* ldsS = (const short8*)ldsB;
        #pragma unroll
        for (int ks = 0; ks < 4; ++ks) {
            short8 bfr[8];
            #pragma unroll
            for (int tc = 0; tc < 8; ++tc) {
                const int brow  = tc * 16 + c;        // B-operand: n = lane&15
                const int chunk = ks * 4 + q;         // k-chunk = (ks*32 + q*8)/8
                bfr[tc] = ldsS[brow * 16 + (chunk ^ (brow & 15))];
            }
            #pragma unroll
            for (int tr = 0; tr < 2; ++tr)
                #pragma unroll
                for (int tc = 0; tc < 8; ++tc)
                    acc[tr][tc] = __builtin_amdgcn_mfma_f32_16x16x32_bf16(
                        afrag[tr][ks], bfr[tc], acc[tr][tc], 0, 0, 0);
        }

        // ---- epilogue: exp, diagonal/label masking, per-row accumulate ----
        #pragma unroll
        for (int tr = 0; tr < 2; ++tr) {
            const int rtile = rw + tr * 16;
            #pragma unroll
            for (int tc = 0; tc < 8; ++tc) {
                const bool diag_tile = (rtile == cbase + tc * 16);  // wave-uniform
                const int lc = collab[tc];
                #pragma unroll
                for (int reg = 0; reg < 4; ++reg) {
                    float v = __expf(acc[tr][tc][reg] * invT);
                    if (diag_tile && (q * 4 + reg) == c) v = 0.f;  // r == c
                    tot_a[tr][reg] += v;
                    if (rowlab[tr][reg] == lc) pos_a[tr][reg] += v;
                }
            }
        }
        __syncthreads();  // all LDS reads done before next staging
    }

    // ---- reduce over the 16 column-lanes, then one atomic per row ----
    #pragma unroll
    for (int tr = 0; tr < 2; ++tr)
        #pragma unroll
        for (int reg = 0; reg < 4; ++reg) {
            float t = tot_a[tr][reg];
            float p = pos_a[tr][reg];
            #pragma unroll
            for (int m = 1; m < 16; m <<= 1) {
                t += __shfl_xor(t, m, 64);
                p += __shfl_xor(p, m, 64);
            }
            if (c == 0) {
                const int r = rw + tr * 16 + q * 4 + reg;
                atomicAdd(&tot[r], t);
                atomicAdd(&pos[r], p);
            }
        }
}

// Finalize: label histogram -> valid mask; per-row loss; mean over valid rows.
__global__ void cl_finalize(const int* __restrict__ labels,
                            const float* __restrict__ tot,
                            const float* __restrict__ pos,
                            float* __restrict__ out)
{
    __shared__ int hist[128];
    __shared__ float ssum[4], scnt[4];
    const int tid = threadIdx.x;
    if (tid < 128) hist[tid] = 0;
    __syncthreads();
    for (int i = tid; i < N; i += 256) atomicAdd(&hist[labels[i] & 127], 1);
    __syncthreads();

    float lsum = 0.f, lcnt = 0.f;
    for (int i = tid; i < N; i += 256) {
        const int cc = hist[labels[i] & 127] - 1;   // #off-diag same-label
        const float loss = -__logf(pos[i] / (tot[i] + 1e-8f) + 1e-8f);
        if (cc > 0) { lsum += loss; lcnt += 1.f; }
    }
    #pragma unroll
    for (int m = 1; m < 64; m <<= 1) {
        lsum += __shfl_xor(lsum, m, 64);
        lcnt += __shfl_xor(lcnt, m, 64);
    }
    const int wave = tid >> 6;
    if ((tid & 63) == 0) { ssum[wave] = lsum; scnt[wave] = lcnt; }
    __syncthreads();
    if (tid == 0) {
        const float s = ssum[0] + ssum[1] + ssum[2] + ssum[3];
        const float n = scnt[0] + scnt[1] + scnt[2] + scnt[3];
        out[0] = (n > 0.f) ? s / fmaxf(n, 1.f) : 0.f;
    }
}

extern "C" void kernel_launch(void* const* d_in, const int* in_sizes, int n_in,
                              void* d_out, int out_size, void* d_ws, size_t ws_size,
                              hipStream_t stream) {
    const float* emb   = (const float*)d_in[0];
    const int* labels  = (const int*)d_in[1];
    float* tot = (float*)d_ws;
    float* pos = tot + N;

    hipMemsetAsync(d_ws, 0, 2 * N * sizeof(float), stream);
    cl_main<<<dim3(64, 8), 256, 0, stream>>>(emb, labels, tot, pos);
    cl_finalize<<<1, 256, 0, stream>>>(labels, tot, pos, (float*)d_out);
}